// Round 7
// baseline (362.305 us; speedup 1.0000x reference)
//
#include <hip/hip_runtime.h>
#include <hip/hip_bf16.h>
#include <stdint.h>

#define B_ 64
#define N_ 4096
#define D_ 128
#define S_ 7
#define EPS_ 1e-8f
#define LN_EPS_ 1e-5f
#define SC_INV 0.08838834764831843f  // 1/sqrt(128)

typedef float  f32x4  __attribute__((ext_vector_type(4)));
typedef __bf16 bf16x8 __attribute__((ext_vector_type(8)));

// wbf (bf16 frag-linear weights) segment offsets (elements)
#define WIH_OFF 0
#define WHH_OFF 49152
#define W1_OFF  98304
#define W2_OFF  131072
#define WQ_OFF  163840
#define WKT_OFF 180224
#define WV_OFF  196608
#define WBF_TOT 212992

__device__ __forceinline__ uint16_t f2bfbits(float f) {
    uint32_t x = __float_as_uint(f);
    return (uint16_t)((x + 0x7fffu + ((x >> 16) & 1u)) >> 16);  // RNE
}
__device__ __forceinline__ uint32_t pk2(float a, float b) {
    return (uint32_t)f2bfbits(a) | ((uint32_t)f2bfbits(b) << 16);
}

// ---------------------------------------------------------------------------
// K_PREP (4096 blocks x 256): streaming LN(x) -> bf16 xn frag-linear.
// NEW lane assignment: lane l owns row=l&15, d = k0*32 + (l>>4)*8 + j.
// Store per k0 is xn + (tile*4+k0)*512 + lane*8 -> one coalesced 16B uint4
// per lane (wave writes 1024B contiguous). Same [n][d] layout as before;
// only the producer's lane mapping changed. LN stats unchanged (row is
// spread over lanes {lm, lm+16, lm+32, lm+48} -> shfl_xor 16/32).
// ---------------------------------------------------------------------------
__global__ __launch_bounds__(256) void k_prep_xn(
    const float* __restrict__ x, const float* __restrict__ lng,
    const float* __restrict__ lnb, uint16_t* __restrict__ xn) {
    const int t = threadIdx.x, wv = t >> 6, lane = t & 63;
    const int lm = lane & 15, hi = lane >> 4;
    const long row = (long)blockIdx.x * 64 + wv * 16 + lm;
    const long ntile = (long)blockIdx.x * 4 + wv;
    const float* xp = x + row * 128 + hi * 8;
    f32x4 xa[4][2];
    #pragma unroll
    for (int k0 = 0; k0 < 4; ++k0) {
        xa[k0][0] = *(const f32x4*)(xp + k0 * 32);
        xa[k0][1] = *(const f32x4*)(xp + k0 * 32 + 4);
    }
    float s = 0.f, sq = 0.f;
    #pragma unroll
    for (int k0 = 0; k0 < 4; ++k0)
        #pragma unroll
        for (int c = 0; c < 2; ++c)
            #pragma unroll
            for (int r = 0; r < 4; ++r) { float v = xa[k0][c][r]; s += v; sq += v * v; }
    s  += __shfl_xor(s, 16);  s  += __shfl_xor(s, 32);
    sq += __shfl_xor(sq, 16); sq += __shfl_xor(sq, 32);
    float mean = s * (1.0f / 128.0f);
    float var  = sq * (1.0f / 128.0f) - mean * mean;
    float rs   = rsqrtf(var + LN_EPS_);
    #pragma unroll
    for (int k0 = 0; k0 < 4; ++k0) {
        f32x4 g0 = *(const f32x4*)(lng + k0 * 32 + hi * 8);
        f32x4 g1 = *(const f32x4*)(lng + k0 * 32 + hi * 8 + 4);
        f32x4 b0 = *(const f32x4*)(lnb + k0 * 32 + hi * 8);
        f32x4 b1 = *(const f32x4*)(lnb + k0 * 32 + hi * 8 + 4);
        float v[8];
        #pragma unroll
        for (int r = 0; r < 4; ++r) {
            v[r]     = (xa[k0][0][r] - mean) * rs * g0[r] + b0[r];
            v[4 + r] = (xa[k0][1][r] - mean) * rs * g1[r] + b1[r];
        }
        uint4 st;
        st.x = pk2(v[0], v[1]); st.y = pk2(v[2], v[3]);
        st.z = pk2(v[4], v[5]); st.w = pk2(v[6], v[7]);
        *(uint4*)(xn + (ntile * 4 + k0) * 512 + lane * 8) = st;
    }
}

// ---------------------------------------------------------------------------
// K_INIT (448 blocks x 256, one per (b,s)): slots init, LN, q, kq -> kqbf
// frag-linear; kq pad-row zero; wbf weight swizzle (strided). R2-proven.
// ---------------------------------------------------------------------------
__global__ __launch_bounds__(256) void k_init(
    const float* __restrict__ noise, const float* __restrict__ Wk,
    const float* __restrict__ mu, const float* __restrict__ logsigma,
    const float* __restrict__ Wq, const float* __restrict__ lsg,
    const float* __restrict__ lsb,
    const float* __restrict__ Wih, const float* __restrict__ Whh,
    const float* __restrict__ W1, const float* __restrict__ W2,
    const float* __restrict__ Wv,
    float* __restrict__ slots, uint16_t* __restrict__ kqbf,
    uint16_t* __restrict__ wbf) {
    const int t = threadIdx.x;
    __shared__ float sn[128], qr[128];
    __shared__ float red[2];
    const int tid = blockIdx.x * 256 + t;
    const int row = blockIdx.x;           // b*7+s
    const int b = row / 7, s = row - b * 7;
    bool act = t < 128;
    float v = 0.f;
    if (act) {
        float sc = log1pf(__expf(logsigma[t])) + 1e-5f;
        v = mu[t] + sc * noise[row * 128 + t];
        slots[row * 128 + t] = v;
    }
    float sv = act ? v : 0.f;
    #pragma unroll
    for (int m = 1; m < 64; m <<= 1) sv += __shfl_xor(sv, m);
    if (act && (t & 63) == 0) red[t >> 6] = sv;
    __syncthreads();
    float mean = (red[0] + red[1]) * (1.0f / 128.0f);
    __syncthreads();
    float dv = act ? (v - mean) : 0.f;
    float sq = dv * dv;
    #pragma unroll
    for (int m = 1; m < 64; m <<= 1) sq += __shfl_xor(sq, m);
    if (act && (t & 63) == 0) red[t >> 6] = sq;
    __syncthreads();
    float var = (red[0] + red[1]) * (1.0f / 128.0f);
    if (act) sn[t] = dv * rsqrtf(var + LN_EPS_) * lsg[t] + lsb[t];
    __syncthreads();
    if (act) {
        const float4* wr = (const float4*)(Wq + t * 128);
        float acc = 0.f;
        #pragma unroll 8
        for (int j = 0; j < 32; ++j) {
            float4 w = wr[j];
            float4 s4 = *(const float4*)(sn + 4 * j);
            acc += w.x * s4.x + w.y * s4.y + w.z * s4.z + w.w * s4.w;
        }
        qr[t] = acc;
    }
    __syncthreads();
    if (act) {
        float kq = 0.f;
        #pragma unroll 8
        for (int o = 0; o < 128; ++o) kq += qr[o] * Wk[o * 128 + t];
        int elem = (t >> 5) * 512 + (s + 16 * ((t >> 3) & 3)) * 8 + (t & 7);
        kqbf[b * 2048 + elem] = f2bfbits(kq * SC_INV);
    }
    if (tid < 73728) {  // zero kq pad rows s'=7..15
        int bb = tid / 1152, rem = tid - bb * 1152;
        int sp = 7 + (rem >> 7), d = rem & 127;
        int elem = (d >> 5) * 512 + (sp + 16 * ((d >> 3) & 3)) * 8 + (d & 7);
        kqbf[bb * 2048 + elem] = 0;
    }
    for (int e = tid; e < WBF_TOT; e += 448 * 256) {
        const float* W; int C, el, mode = 0;
        if (e < WHH_OFF)      { W = Wih; C = 128; el = e; }
        else if (e < W1_OFF)  { W = Whh; C = 128; el = e - WHH_OFF; }
        else if (e < W2_OFF)  { W = W1;  C = 128; el = e - W1_OFF; }
        else if (e < WQ_OFF)  { W = W2;  C = 256; el = e - W2_OFF; }
        else if (e < WKT_OFF) { W = Wq;  C = 128; el = e - WQ_OFF; }
        else if (e < WV_OFF)  { W = Wk;  C = 128; el = e - WKT_OFF; mode = 1; }
        else                  { W = Wv;  C = 128; el = e - WV_OFF; }
        int tile = el >> 9, within = el & 511;
        int lp = within >> 3, j = within & 7;
        int lm_ = lp & 15, qd_ = lp >> 4;
        float w;
        if (!mode) {
            int ktN = C >> 5, ot = tile / ktN, kt = tile - ot * ktN;
            w = W[(ot * 16 + lm_) * C + kt * 32 + qd_ * 8 + j];
        } else {  // Wk non-transposed: B[k=o][col=d']
            int dt = tile >> 2, kt = tile & 3;
            w = W[(kt * 32 + qd_ * 8 + j) * 128 + dt * 16 + lm_];
        }
        wbf[e] = f2bfbits(w);
    }
}

// ---------------------------------------------------------------------------
// K2 per iter (1024 blocks = b*16+chunk, 4 waves x 64 n rows): R2-proven.
//   scoresT via mfma(kq, xn); cheap softmax over s (2 shfl); PV via per-wave
//   LDS stage + scalar transpose reads; stage aliased with partials buffer.
// ---------------------------------------------------------------------------
__global__ __launch_bounds__(256, 4) void k_attn(
    const uint16_t* __restrict__ xn, const uint16_t* __restrict__ kqbf,
    float* __restrict__ upart, float* __restrict__ cpart) {
    __shared__ __align__(16) uint16_t stage[4][32 * 132];  // per-wave; aliased as part[7][132] f32
    __shared__ __align__(16) uint16_t als[4][16 * 36];     // per-wave attn frags (pitch 36)
    __shared__ float bsum[4][8];
    const int t = threadIdx.x, wv = t >> 6, lane = t & 63;
    const int lm = lane & 15, qd = lane >> 4;
    const int b = blockIdx.x >> 4, chunk = blockIdx.x & 15;
    const int ntb = b * 256 + chunk * 16 + wv * 4;  // global 16-row tile base
    const int sbase = qd * 4;                       // this lane's s rows

    bf16x8 kqf[4];
    #pragma unroll
    for (int k0 = 0; k0 < 4; ++k0)
        kqf[k0] = *(const bf16x8*)(kqbf + b * 2048 + k0 * 512 + lane * 8);

    uint16_t* xw = stage[wv];
    float* prt = (float*)stage[wv];  // reused for partials after last stage read
    uint16_t* aw = als[wv];
    f32x4 uacc[8];
    #pragma unroll
    for (int i = 0; i < 8; ++i) uacc[i] = (f32x4){0.f, 0.f, 0.f, 0.f};
    f32x4 csl = {0.f, 0.f, 0.f, 0.f};

    #pragma unroll
    for (int sub = 0; sub < 2; ++sub) {
        bf16x8 xf[2][4];
        #pragma unroll
        for (int nt = 0; nt < 2; ++nt)
            #pragma unroll
            for (int k0 = 0; k0 < 4; ++k0)
                xf[nt][k0] = *(const bf16x8*)(xn +
                    ((long)(ntb + sub * 2 + nt) * 4 + k0) * 512 + lane * 8);
        // stage to LDS n-major (for the transposed PV operand)
        #pragma unroll
        for (int nt = 0; nt < 2; ++nt)
            #pragma unroll
            for (int k0 = 0; k0 < 4; ++k0) {
                int base = (nt * 16 + lm) * 132 + k0 * 32 + qd * 8;
                const uint2* src = (const uint2*)&xf[nt][k0];
                *(uint2*)(xw + base)     = src[0];
                *(uint2*)(xw + base + 4) = src[1];
            }
        // scoresT: lane holds sc[s=sbase+r][n=nt*16+lm]
        f32x4 sc[2];
        #pragma unroll
        for (int nt = 0; nt < 2; ++nt) {
            f32x4 acc = {0.f, 0.f, 0.f, 0.f};
            #pragma unroll
            for (int k0 = 0; k0 < 4; ++k0)
                acc = __builtin_amdgcn_mfma_f32_16x16x32_bf16(kqf[k0], xf[nt][k0], acc, 0, 0, 0);
            sc[nt] = acc;
        }
        // softmax over s (S=7; kq pad rows are zero -> masked out)
        #pragma unroll
        for (int nt = 0; nt < 2; ++nt) {
            float mx = -1e30f;
            #pragma unroll
            for (int r = 0; r < 4; ++r)
                if (sbase + r < 7) mx = fmaxf(mx, sc[nt][r]);
            mx = fmaxf(mx, __shfl_xor(mx, 16));
            mx = fmaxf(mx, __shfl_xor(mx, 32));
            float e[4], tot = 0.f;
            #pragma unroll
            for (int r = 0; r < 4; ++r) {
                e[r] = (sbase + r < 7) ? __expf(sc[nt][r] - mx) : 0.f;
                tot += e[r];
            }
            tot += __shfl_xor(tot, 16);
            tot += __shfl_xor(tot, 32);
            float inv = 1.0f / tot;
            #pragma unroll
            for (int r = 0; r < 4; ++r) {
                float a_ = (sbase + r < 7) ? e[r] * inv + EPS_ : 0.f;
                csl[r] += a_;
                aw[(sbase + r) * 36 + nt * 16 + lm] = f2bfbits(a_);
            }
        }
        // A-frag for PV: attnT[s=lm][k=n=qd*8+j]
        union { uint2 u[2]; bf16x8 v; } cva;
        cva.u[0] = *(const uint2*)(aw + lm * 36 + qd * 8);
        cva.u[1] = *(const uint2*)(aw + lm * 36 + qd * 8 + 4);
        bf16x8 afr = cva.v;
        // PV: B = xn^T frag via scalar transpose reads from stage
        #pragma unroll
        for (int dt = 0; dt < 8; ++dt) {
            bf16x8 bfr;
            #pragma unroll
            for (int j = 0; j < 8; ++j)
                bfr[j] = ((const __bf16*)xw)[(qd * 8 + j) * 132 + dt * 16 + lm];
            uacc[dt] = __builtin_amdgcn_mfma_f32_16x16x32_bf16(afr, bfr, uacc[dt], 0, 0, 0);
        }
    }
    // csum: reduce over n=lm (16 lanes); lane then holds sum for s=sbase+r
    #pragma unroll
    for (int m = 1; m < 16; m <<= 1) {
        csl[0] += __shfl_xor(csl[0], m);
        csl[1] += __shfl_xor(csl[1], m);
        csl[2] += __shfl_xor(csl[2], m);
        csl[3] += __shfl_xor(csl[3], m);
    }
    if (lm == 0) {
        #pragma unroll
        for (int r = 0; r < 4; ++r) {
            int s = sbase + r;
            if (s < 7) bsum[wv][s] = csl[r];
        }
    }
    // partials into the (now dead) stage buffer
    #pragma unroll
    for (int dt = 0; dt < 8; ++dt)
        #pragma unroll
        for (int r = 0; r < 4; ++r) {
            int s = sbase + r;
            if (s < 7) prt[s * 132 + dt * 16 + lm] = uacc[dt][r];
        }
    __syncthreads();
    if (t < 128) {
        const float* p0 = (const float*)stage[0];
        const float* p1 = (const float*)stage[1];
        const float* p2 = (const float*)stage[2];
        const float* p3 = (const float*)stage[3];
        #pragma unroll
        for (int s = 0; s < 7; ++s) {
            int o = s * 132 + t;
            upart[((b * 16 + chunk) * 7 + s) * 128 + t] = p0[o] + p1[o] + p2[o] + p3[o];
        }
    }
    if (t < 7)
        cpart[(b * 16 + chunk) * 7 + t] = bsum[0][t] + bsum[1][t] + bsum[2][t] + bsum[3][t];
}

// ---------------------------------------------------------------------------
// K3 (one block per batch, 256 thr): P = reduce(upart); u = (P@Wv^T)/csum via
// MFMA; GRU via MFMA; LN; MLP via MFMA; dst; if hasq: LN + q + kq -> kqbf.
// R2-proven.
// ---------------------------------------------------------------------------
__global__ __launch_bounds__(256) void k_fused(
    const float* __restrict__ upart, const float* __restrict__ cpart,
    float* __restrict__ slots, const uint16_t* __restrict__ wbf,
    const float* __restrict__ bih, const float* __restrict__ bhh,
    const float* __restrict__ gm, const float* __restrict__ bm,
    const float* __restrict__ b1, const float* __restrict__ b2,
    const float* __restrict__ lsg, const float* __restrict__ lsb,
    uint16_t* __restrict__ kqbf, float* __restrict__ dst, int hasq) {
    __shared__ float uf[16][132];     // u, then hn, then sn(for q)
    __shared__ float hf[16][132];     // h, then out
    __shared__ float slf[16][132];    // P, then LN(hn), then q
    __shared__ float hidl[16][264];   // MLP hidden, then kq
    __shared__ float glg[7][776];
    __shared__ float csl[7];
    const int b = blockIdx.x;
    const int t = threadIdx.x, wv = t >> 6, lane = t & 63;
    const int lm = lane & 15, qd = lane >> 4;

    if (t < 7) {
        float c = 0.f;
        #pragma unroll
        for (int i = 0; i < 16; ++i) c += cpart[(b * 16 + i) * 7 + t];
        csl[t] = c;
    }
    for (int idx = t; idx < 896; idx += 256) {
        int s = idx >> 7, d = idx & 127;
        float acc = 0.f;
        #pragma unroll
        for (int i = 0; i < 16; ++i) acc += upart[((b * 16 + i) * 7 + s) * 128 + d];
        slf[s][d] = acc;                       // P (pre-Wv, pre-renorm)
        hf[s][d] = slots[(b * 7 + s) * 128 + d];
    }
    __syncthreads();

    // u = (P @ Wv^T) / csum
    {
        bf16x8 apb[4];
        #pragma unroll
        for (int k0 = 0; k0 < 4; ++k0)
            #pragma unroll
            for (int j = 0; j < 8; ++j) apb[k0][j] = (__bf16)slf[lm][k0 * 32 + qd * 8 + j];
        #pragma unroll
        for (int i = 0; i < 2; ++i) {
            int dt = wv * 2 + i;
            f32x4 acc = {0.f, 0.f, 0.f, 0.f};
            #pragma unroll
            for (int k0 = 0; k0 < 4; ++k0) {
                bf16x8 bf = *(const bf16x8*)(wbf + WV_OFF + ((dt * 4 + k0) << 9) + lane * 8);
                acc = __builtin_amdgcn_mfma_f32_16x16x32_bf16(apb[k0], bf, acc, 0, 0, 0);
            }
            #pragma unroll
            for (int r = 0; r < 4; ++r) {
                int s = qd * 4 + r;
                if (s < 7) uf[s][dt * 16 + lm] = acc[r] / csl[s];
            }
        }
    }
    __syncthreads();

    bf16x8 au[4], ah[4];
    #pragma unroll
    for (int k0 = 0; k0 < 4; ++k0)
        #pragma unroll
        for (int j = 0; j < 8; ++j) {
            au[k0][j] = (__bf16)uf[lm][k0 * 32 + qd * 8 + j];
            ah[k0][j] = (__bf16)hf[lm][k0 * 32 + qd * 8 + j];
        }
    {
        const int ih = (wv < 2);
        const uint16_t* W = wbf + (ih ? WIH_OFF : WHH_OFF);
        const int base = ih ? 0 : 384;
        const int w2 = wv & 1;
        #pragma unroll
        for (int i = 0; i < 12; ++i) {
            int ot = w2 * 12 + i;
            f32x4 acc = {0.f, 0.f, 0.f, 0.f};
            #pragma unroll
            for (int k0 = 0; k0 < 4; ++k0) {
                bf16x8 bf = *(const bf16x8*)(W + ((ot * 4 + k0) << 9) + lane * 8);
                acc = __builtin_amdgcn_mfma_f32_16x16x32_bf16(ih ? au[k0] : ah[k0], bf, acc, 0, 0, 0);
            }
            #pragma unroll
            for (int r = 0; r < 4; ++r) {
                int s = qd * 4 + r;
                if (s < 7) glg[s][base + ot * 16 + lm] = acc[r];
            }
        }
    }
    __syncthreads();

    for (int idx = t; idx < 896; idx += 256) {
        int s = idx >> 7, d = idx & 127;
        float xr = glg[s][d] + bih[d];
        float xz = glg[s][128 + d] + bih[128 + d];
        float xg = glg[s][256 + d] + bih[256 + d];
        float hr = glg[s][384 + d] + bhh[d];
        float hz = glg[s][512 + d] + bhh[128 + d];
        float hg = glg[s][640 + d] + bhh[256 + d];
        float r = 1.f / (1.f + __expf(-(xr + hr)));
        float z = 1.f / (1.f + __expf(-(xz + hz)));
        float n = tanhf(xg + r * hg);
        uf[s][d] = (1.f - z) * n + z * hf[s][d];
    }
    __syncthreads();

    for (int s = wv; s < 7; s += 4) {
        float a0 = uf[s][2 * lane], a1 = uf[s][2 * lane + 1];
        float sm = a0 + a1, sq = a0 * a0 + a1 * a1;
        #pragma unroll
        for (int m = 1; m < 64; m <<= 1) { sm += __shfl_xor(sm, m); sq += __shfl_xor(sq, m); }
        float mean = sm * (1.0f / 128.0f);
        float var = sq * (1.0f / 128.0f) - mean * mean;
        float rs = rsqrtf(var + LN_EPS_);
        slf[s][2 * lane]     = (a0 - mean) * rs * gm[2 * lane] + bm[2 * lane];
        slf[s][2 * lane + 1] = (a1 - mean) * rs * gm[2 * lane + 1] + bm[2 * lane + 1];
    }
    __syncthreads();

    bf16x8 as_[4];
    #pragma unroll
    for (int k0 = 0; k0 < 4; ++k0)
        #pragma unroll
        for (int j = 0; j < 8; ++j) as_[k0][j] = (__bf16)slf[lm][k0 * 32 + qd * 8 + j];
    #pragma unroll
    for (int i = 0; i < 4; ++i) {
        int ot = wv * 4 + i;
        f32x4 acc = {0.f, 0.f, 0.f, 0.f};
        #pragma unroll
        for (int k0 = 0; k0 < 4; ++k0) {
            bf16x8 bf = *(const bf16x8*)(wbf + W1_OFF + ((ot * 4 + k0) << 9) + lane * 8);
            acc = __builtin_amdgcn_mfma_f32_16x16x32_bf16(as_[k0], bf, acc, 0, 0, 0);
        }
        #pragma unroll
        for (int r = 0; r < 4; ++r) {
            int s = qd * 4 + r;
            if (s < 7) hidl[s][ot * 16 + lm] = fmaxf(acc[r] + b1[ot * 16 + lm], 0.f);
        }
    }
    __syncthreads();

    bf16x8 ahd[8];
    #pragma unroll
    for (int k0 = 0; k0 < 8; ++k0)
        #pragma unroll
        for (int j = 0; j < 8; ++j) ahd[k0][j] = (__bf16)hidl[lm][k0 * 32 + qd * 8 + j];
    #pragma unroll
    for (int i = 0; i < 2; ++i) {
        int ot = wv * 2 + i;
        f32x4 acc = {0.f, 0.f, 0.f, 0.f};
        #pragma unroll
        for (int k0 = 0; k0 < 8; ++k0) {
            bf16x8 bf = *(const bf16x8*)(wbf + W2_OFF + ((ot * 8 + k0) << 9) + lane * 8);
            acc = __builtin_amdgcn_mfma_f32_16x16x32_bf16(ahd[k0], bf, acc, 0, 0, 0);
        }
        #pragma unroll
        for (int r = 0; r < 4; ++r) {
            int s = qd * 4 + r;
            if (s < 7) {
                float v = slf[s][ot * 16 + lm] + acc[r] + b2[ot * 16 + lm];
                hf[s][ot * 16 + lm] = v;
                dst[(b * 7 + s) * 128 + ot * 16 + lm] = v;
            }
        }
    }
    if (hasq) {
        __syncthreads();
        // sn = LN_slots(out) -> uf
        for (int s = wv; s < 7; s += 4) {
            float a0 = hf[s][2 * lane], a1 = hf[s][2 * lane + 1];
            float sm = a0 + a1, sq = a0 * a0 + a1 * a1;
            #pragma unroll
            for (int m = 1; m < 64; m <<= 1) { sm += __shfl_xor(sm, m); sq += __shfl_xor(sq, m); }
            float mean = sm * (1.0f / 128.0f);
            float var = sq * (1.0f / 128.0f) - mean * mean;
            float rs = rsqrtf(var + LN_EPS_);
            uf[s][2 * lane]     = (a0 - mean) * rs * lsg[2 * lane] + lsb[2 * lane];
            uf[s][2 * lane + 1] = (a1 - mean) * rs * lsg[2 * lane + 1] + lsb[2 * lane + 1];
        }
        __syncthreads();
        // q = sn @ Wq^T -> slf
        bf16x8 an[4];
        #pragma unroll
        for (int k0 = 0; k0 < 4; ++k0)
            #pragma unroll
            for (int j = 0; j < 8; ++j) an[k0][j] = (__bf16)uf[lm][k0 * 32 + qd * 8 + j];
        #pragma unroll
        for (int i = 0; i < 2; ++i) {
            int ot = wv * 2 + i;
            f32x4 acc = {0.f, 0.f, 0.f, 0.f};
            #pragma unroll
            for (int k0 = 0; k0 < 4; ++k0) {
                bf16x8 bf = *(const bf16x8*)(wbf + WQ_OFF + ((ot * 4 + k0) << 9) + lane * 8);
                acc = __builtin_amdgcn_mfma_f32_16x16x32_bf16(an[k0], bf, acc, 0, 0, 0);
            }
            #pragma unroll
            for (int r = 0; r < 4; ++r) {
                int s = qd * 4 + r;
                if (s < 7) slf[s][ot * 16 + lm] = acc[r];
            }
        }
        __syncthreads();
        // kq = q @ Wk -> hidl
        bf16x8 aq[4];
        #pragma unroll
        for (int k0 = 0; k0 < 4; ++k0)
            #pragma unroll
            for (int j = 0; j < 8; ++j) aq[k0][j] = (__bf16)slf[lm][k0 * 32 + qd * 8 + j];
        #pragma unroll
        for (int i = 0; i < 2; ++i) {
            int dt = wv * 2 + i;
            f32x4 acc = {0.f, 0.f, 0.f, 0.f};
            #pragma unroll
            for (int k0 = 0; k0 < 4; ++k0) {
                bf16x8 bf = *(const bf16x8*)(wbf + WKT_OFF + ((dt * 4 + k0) << 9) + lane * 8);
                acc = __builtin_amdgcn_mfma_f32_16x16x32_bf16(aq[k0], bf, acc, 0, 0, 0);
            }
            #pragma unroll
            for (int r = 0; r < 4; ++r) {
                int s = qd * 4 + r;
                if (s < 7) hidl[s][dt * 16 + lm] = acc[r];
            }
        }
        __syncthreads();
        // frag-linear bf16 store of kq*SC
        {
            int kt = t >> 6, lp = t & 63;
            int lmp = lp & 15, qdp = lp >> 4;
            uint16_t h[8];
            #pragma unroll
            for (int j = 0; j < 8; ++j)
                h[j] = (lmp < 7) ? f2bfbits(hidl[lmp][kt * 32 + qdp * 8 + j] * SC_INV) : (uint16_t)0;
            uint4 st;
            st.x = (uint32_t)h[0] | ((uint32_t)h[1] << 16);
            st.y = (uint32_t)h[2] | ((uint32_t)h[3] << 16);
            st.z = (uint32_t)h[4] | ((uint32_t)h[5] << 16);
            st.w = (uint32_t)h[6] | ((uint32_t)h[7] << 16);
            *(uint4*)(kqbf + b * 2048 + t * 8) = st;
        }
    }
}

// ---------------------------------------------------------------------------
extern "C" void kernel_launch(void* const* d_in, const int* in_sizes, int n_in,
                              void* d_out, int out_size, void* d_ws, size_t ws_size,
                              hipStream_t stream) {
    const float* x    = (const float*)d_in[0];
    const float* nz   = (const float*)d_in[1];
    const float* Wq   = (const float*)d_in[2];
    const float* Wk   = (const float*)d_in[3];
    const float* Wv   = (const float*)d_in[4];
    const float* ling = (const float*)d_in[5];
    const float* linb = (const float*)d_in[6];
    const float* lsg  = (const float*)d_in[7];
    const float* lsb  = (const float*)d_in[8];
    const float* lmg  = (const float*)d_in[9];
    const float* lmb  = (const float*)d_in[10];
    const float* Wih  = (const float*)d_in[11];
    const float* Whh  = (const float*)d_in[12];
    const float* bih  = (const float*)d_in[13];
    const float* bhh  = (const float*)d_in[14];
    const float* W1   = (const float*)d_in[15];
    const float* b1   = (const float*)d_in[16];
    const float* W2   = (const float*)d_in[17];
    const float* b2   = (const float*)d_in[18];
    const float* mu   = (const float*)d_in[19];
    const float* lsig = (const float*)d_in[20];

    char* wsb = (char*)d_ws;
    uint16_t* xn    = (uint16_t*)(wsb);                        // 67108864 B
    uint16_t* wbf   = (uint16_t*)(wsb + (size_t)67108864);     // 425984 B
    uint16_t* kqbf  = (uint16_t*)(wsb + (size_t)67534848);     // 262144 B
    float*    slots = (float*)  (wsb + (size_t)67796992);      // 229376 B
    float*    upart = (float*)  (wsb + (size_t)68026368);      // 3670016 B
    float*    cpart = (float*)  (wsb + (size_t)71696384);      // 28672 B

    k_prep_xn<<<4096, 256, 0, stream>>>(x, ling, linb, xn);
    k_init<<<448, 256, 0, stream>>>(nz, Wk, mu, lsig, Wq, lsg, lsb,
                                    Wih, Whh, W1, W2, Wv, slots, kqbf, wbf);
    for (int it = 0; it < 3; ++it) {
        float* dst = (it == 2) ? (float*)d_out : slots;
        k_attn<<<1024, 256, 0, stream>>>(xn, kqbf, upart, cpart);
        k_fused<<<64, 256, 0, stream>>>(upart, cpart, slots, wbf, bih, bhh,
                                        lmg, lmb, b1, b2, lsg, lsb,
                                        kqbf, dst, (it < 2) ? 1 : 0);
    }
}

// Round 8
// 351.728 us; speedup vs baseline: 1.0301x; 1.0301x over previous
//
#include <hip/hip_runtime.h>
#include <hip/hip_bf16.h>
#include <stdint.h>

#define B_ 64
#define N_ 4096
#define D_ 128
#define S_ 7
#define EPS_ 1e-8f
#define LN_EPS_ 1e-5f
#define SC_INV 0.08838834764831843f  // 1/sqrt(128)

typedef float  f32x4  __attribute__((ext_vector_type(4)));
typedef __bf16 bf16x8 __attribute__((ext_vector_type(8)));

// wbf (bf16 frag-linear weights) segment offsets (elements)
#define WIH_OFF 0
#define WHH_OFF 49152
#define W1_OFF  98304
#define W2_OFF  131072
#define WQ_OFF  163840
#define WKT_OFF 180224
#define WV_OFF  196608
#define WBF_TOT 212992

__device__ __forceinline__ uint16_t f2bfbits(float f) {
    uint32_t x = __float_as_uint(f);
    return (uint16_t)((x + 0x7fffu + ((x >> 16) & 1u)) >> 16);  // RNE
}
__device__ __forceinline__ uint32_t pk2(float a, float b) {
    return (uint32_t)f2bfbits(a) | ((uint32_t)f2bfbits(b) << 16);
}

// ---------------------------------------------------------------------------
// K0 merged (4544 blocks x 256):
//   blocks [0,448): init path — slots init, LN, q, kq -> kqbf frag-linear;
//                   kq pad-row zero; wbf weight swizzle (R2-proven; hides
//                   under the memory-bound prep blocks).
//   blocks [448,4544): prep path — streaming LN(x) -> bf16 xn frag-linear
//                   with R7's coalesced lane mapping: lane l owns row=l&15,
//                   d = k0*32 + (l>>4)*8 + j; one 16B uint4 store per k0
//                   (wave writes 1024B contiguous).
// ---------------------------------------------------------------------------
__global__ __launch_bounds__(256) void k_init_prep(
    const float* __restrict__ noise, const float* __restrict__ Wk,
    const float* __restrict__ mu, const float* __restrict__ logsigma,
    const float* __restrict__ Wq, const float* __restrict__ lsg,
    const float* __restrict__ lsb,
    const float* __restrict__ Wih, const float* __restrict__ Whh,
    const float* __restrict__ W1, const float* __restrict__ W2,
    const float* __restrict__ Wv,
    float* __restrict__ slots, uint16_t* __restrict__ kqbf,
    uint16_t* __restrict__ wbf,
    const float* __restrict__ x, const float* __restrict__ lng,
    const float* __restrict__ lnb, uint16_t* __restrict__ xn) {
    const int t = threadIdx.x;
    if (blockIdx.x < 448) {
        // ------------------- init path -------------------
        __shared__ float sn[128], qr[128];
        __shared__ float red[2];
        const int tid = blockIdx.x * 256 + t;
        const int row = blockIdx.x;           // b*7+s
        const int b = row / 7, s = row - b * 7;
        bool act = t < 128;
        float v = 0.f;
        if (act) {
            float sc = log1pf(__expf(logsigma[t])) + 1e-5f;
            v = mu[t] + sc * noise[row * 128 + t];
            slots[row * 128 + t] = v;
        }
        float sv = act ? v : 0.f;
        #pragma unroll
        for (int m = 1; m < 64; m <<= 1) sv += __shfl_xor(sv, m);
        if (act && (t & 63) == 0) red[t >> 6] = sv;
        __syncthreads();
        float mean = (red[0] + red[1]) * (1.0f / 128.0f);
        __syncthreads();
        float dv = act ? (v - mean) : 0.f;
        float sq = dv * dv;
        #pragma unroll
        for (int m = 1; m < 64; m <<= 1) sq += __shfl_xor(sq, m);
        if (act && (t & 63) == 0) red[t >> 6] = sq;
        __syncthreads();
        float var = (red[0] + red[1]) * (1.0f / 128.0f);
        if (act) sn[t] = dv * rsqrtf(var + LN_EPS_) * lsg[t] + lsb[t];
        __syncthreads();
        if (act) {
            const float4* wr = (const float4*)(Wq + t * 128);
            float acc = 0.f;
            #pragma unroll 8
            for (int j = 0; j < 32; ++j) {
                float4 w = wr[j];
                float4 s4 = *(const float4*)(sn + 4 * j);
                acc += w.x * s4.x + w.y * s4.y + w.z * s4.z + w.w * s4.w;
            }
            qr[t] = acc;
        }
        __syncthreads();
        if (act) {
            float kq = 0.f;
            #pragma unroll 8
            for (int o = 0; o < 128; ++o) kq += qr[o] * Wk[o * 128 + t];
            int elem = (t >> 5) * 512 + (s + 16 * ((t >> 3) & 3)) * 8 + (t & 7);
            kqbf[b * 2048 + elem] = f2bfbits(kq * SC_INV);
        }
        if (tid < 73728) {  // zero kq pad rows s'=7..15
            int bb = tid / 1152, rem = tid - bb * 1152;
            int sp = 7 + (rem >> 7), d = rem & 127;
            int elem = (d >> 5) * 512 + (sp + 16 * ((d >> 3) & 3)) * 8 + (d & 7);
            kqbf[bb * 2048 + elem] = 0;
        }
        for (int e = tid; e < WBF_TOT; e += 448 * 256) {
            const float* W; int C, el, mode = 0;
            if (e < WHH_OFF)      { W = Wih; C = 128; el = e; }
            else if (e < W1_OFF)  { W = Whh; C = 128; el = e - WHH_OFF; }
            else if (e < W2_OFF)  { W = W1;  C = 128; el = e - W1_OFF; }
            else if (e < WQ_OFF)  { W = W2;  C = 256; el = e - W2_OFF; }
            else if (e < WKT_OFF) { W = Wq;  C = 128; el = e - WQ_OFF; }
            else if (e < WV_OFF)  { W = Wk;  C = 128; el = e - WKT_OFF; mode = 1; }
            else                  { W = Wv;  C = 128; el = e - WV_OFF; }
            int tile = el >> 9, within = el & 511;
            int lp = within >> 3, j = within & 7;
            int lm_ = lp & 15, qd_ = lp >> 4;
            float w;
            if (!mode) {
                int ktN = C >> 5, ot = tile / ktN, kt = tile - ot * ktN;
                w = W[(ot * 16 + lm_) * C + kt * 32 + qd_ * 8 + j];
            } else {  // Wk non-transposed: B[k=o][col=d']
                int dt = tile >> 2, kt = tile & 3;
                w = W[(kt * 32 + qd_ * 8 + j) * 128 + dt * 16 + lm_];
            }
            wbf[e] = f2bfbits(w);
        }
        return;
    }
    // ------------------- prep path (R7 coalesced-store) -------------------
    const int pid = blockIdx.x - 448;
    const int wv = t >> 6, lane = t & 63;
    const int lm = lane & 15, hi = lane >> 4;
    const long row = (long)pid * 64 + wv * 16 + lm;
    const long ntile = (long)pid * 4 + wv;
    const float* xp = x + row * 128 + hi * 8;
    f32x4 xa[4][2];
    #pragma unroll
    for (int k0 = 0; k0 < 4; ++k0) {
        xa[k0][0] = *(const f32x4*)(xp + k0 * 32);
        xa[k0][1] = *(const f32x4*)(xp + k0 * 32 + 4);
    }
    float s = 0.f, sq = 0.f;
    #pragma unroll
    for (int k0 = 0; k0 < 4; ++k0)
        #pragma unroll
        for (int c = 0; c < 2; ++c)
            #pragma unroll
            for (int r = 0; r < 4; ++r) { float v = xa[k0][c][r]; s += v; sq += v * v; }
    s  += __shfl_xor(s, 16);  s  += __shfl_xor(s, 32);
    sq += __shfl_xor(sq, 16); sq += __shfl_xor(sq, 32);
    float mean = s * (1.0f / 128.0f);
    float var  = sq * (1.0f / 128.0f) - mean * mean;
    float rs   = rsqrtf(var + LN_EPS_);
    #pragma unroll
    for (int k0 = 0; k0 < 4; ++k0) {
        f32x4 g0 = *(const f32x4*)(lng + k0 * 32 + hi * 8);
        f32x4 g1 = *(const f32x4*)(lng + k0 * 32 + hi * 8 + 4);
        f32x4 b0 = *(const f32x4*)(lnb + k0 * 32 + hi * 8);
        f32x4 b1 = *(const f32x4*)(lnb + k0 * 32 + hi * 8 + 4);
        float v[8];
        #pragma unroll
        for (int r = 0; r < 4; ++r) {
            v[r]     = (xa[k0][0][r] - mean) * rs * g0[r] + b0[r];
            v[4 + r] = (xa[k0][1][r] - mean) * rs * g1[r] + b1[r];
        }
        uint4 st;
        st.x = pk2(v[0], v[1]); st.y = pk2(v[2], v[3]);
        st.z = pk2(v[4], v[5]); st.w = pk2(v[6], v[7]);
        *(uint4*)(xn + (ntile * 4 + k0) * 512 + lane * 8) = st;
    }
}

// ---------------------------------------------------------------------------
// K2 per iter (1024 blocks = b*16+chunk, 4 waves x 64 n rows): R2-proven,
// plus T14 issue-early: BOTH subs' xn loads hoisted before sub0's compute
// (16 frags in flight, ~96 VGPR <= 128 cap at 4 blocks/CU).
// ---------------------------------------------------------------------------
__global__ __launch_bounds__(256, 4) void k_attn(
    const uint16_t* __restrict__ xn, const uint16_t* __restrict__ kqbf,
    float* __restrict__ upart, float* __restrict__ cpart) {
    __shared__ __align__(16) uint16_t stage[4][32 * 132];  // per-wave; aliased as part[7][132] f32
    __shared__ __align__(16) uint16_t als[4][16 * 36];     // per-wave attn frags (pitch 36)
    __shared__ float bsum[4][8];
    const int t = threadIdx.x, wv = t >> 6, lane = t & 63;
    const int lm = lane & 15, qd = lane >> 4;
    const int b = blockIdx.x >> 4, chunk = blockIdx.x & 15;
    const int ntb = b * 256 + chunk * 16 + wv * 4;  // global 16-row tile base
    const int sbase = qd * 4;                       // this lane's s rows

    bf16x8 kqf[4];
    #pragma unroll
    for (int k0 = 0; k0 < 4; ++k0)
        kqf[k0] = *(const bf16x8*)(kqbf + b * 2048 + k0 * 512 + lane * 8);

    // hoist ALL xn loads (both subs) — sub1's latency hides under sub0
    bf16x8 xfs[2][2][4];
    #pragma unroll
    for (int sub = 0; sub < 2; ++sub)
        #pragma unroll
        for (int nt = 0; nt < 2; ++nt)
            #pragma unroll
            for (int k0 = 0; k0 < 4; ++k0)
                xfs[sub][nt][k0] = *(const bf16x8*)(xn +
                    ((long)(ntb + sub * 2 + nt) * 4 + k0) * 512 + lane * 8);

    uint16_t* xw = stage[wv];
    float* prt = (float*)stage[wv];  // reused for partials after last stage read
    uint16_t* aw = als[wv];
    f32x4 uacc[8];
    #pragma unroll
    for (int i = 0; i < 8; ++i) uacc[i] = (f32x4){0.f, 0.f, 0.f, 0.f};
    f32x4 csl = {0.f, 0.f, 0.f, 0.f};

    #pragma unroll
    for (int sub = 0; sub < 2; ++sub) {
        // stage to LDS n-major (for the transposed PV operand)
        #pragma unroll
        for (int nt = 0; nt < 2; ++nt)
            #pragma unroll
            for (int k0 = 0; k0 < 4; ++k0) {
                int base = (nt * 16 + lm) * 132 + k0 * 32 + qd * 8;
                const uint2* src = (const uint2*)&xfs[sub][nt][k0];
                *(uint2*)(xw + base)     = src[0];
                *(uint2*)(xw + base + 4) = src[1];
            }
        // scoresT: lane holds sc[s=sbase+r][n=nt*16+lm]
        f32x4 sc[2];
        #pragma unroll
        for (int nt = 0; nt < 2; ++nt) {
            f32x4 acc = {0.f, 0.f, 0.f, 0.f};
            #pragma unroll
            for (int k0 = 0; k0 < 4; ++k0)
                acc = __builtin_amdgcn_mfma_f32_16x16x32_bf16(kqf[k0], xfs[sub][nt][k0], acc, 0, 0, 0);
            sc[nt] = acc;
        }
        // softmax over s (S=7; kq pad rows are zero -> masked out)
        #pragma unroll
        for (int nt = 0; nt < 2; ++nt) {
            float mx = -1e30f;
            #pragma unroll
            for (int r = 0; r < 4; ++r)
                if (sbase + r < 7) mx = fmaxf(mx, sc[nt][r]);
            mx = fmaxf(mx, __shfl_xor(mx, 16));
            mx = fmaxf(mx, __shfl_xor(mx, 32));
            float e[4], tot = 0.f;
            #pragma unroll
            for (int r = 0; r < 4; ++r) {
                e[r] = (sbase + r < 7) ? __expf(sc[nt][r] - mx) : 0.f;
                tot += e[r];
            }
            tot += __shfl_xor(tot, 16);
            tot += __shfl_xor(tot, 32);
            float inv = 1.0f / tot;
            #pragma unroll
            for (int r = 0; r < 4; ++r) {
                float a_ = (sbase + r < 7) ? e[r] * inv + EPS_ : 0.f;
                csl[r] += a_;
                aw[(sbase + r) * 36 + nt * 16 + lm] = f2bfbits(a_);
            }
        }
        // A-frag for PV: attnT[s=lm][k=n=qd*8+j]
        union { uint2 u[2]; bf16x8 v; } cva;
        cva.u[0] = *(const uint2*)(aw + lm * 36 + qd * 8);
        cva.u[1] = *(const uint2*)(aw + lm * 36 + qd * 8 + 4);
        bf16x8 afr = cva.v;
        // PV: B = xn^T frag via scalar transpose reads from stage
        #pragma unroll
        for (int dt = 0; dt < 8; ++dt) {
            bf16x8 bfr;
            #pragma unroll
            for (int j = 0; j < 8; ++j)
                bfr[j] = ((const __bf16*)xw)[(qd * 8 + j) * 132 + dt * 16 + lm];
            uacc[dt] = __builtin_amdgcn_mfma_f32_16x16x32_bf16(afr, bfr, uacc[dt], 0, 0, 0);
        }
    }
    // csum: reduce over n=lm (16 lanes); lane then holds sum for s=sbase+r
    #pragma unroll
    for (int m = 1; m < 16; m <<= 1) {
        csl[0] += __shfl_xor(csl[0], m);
        csl[1] += __shfl_xor(csl[1], m);
        csl[2] += __shfl_xor(csl[2], m);
        csl[3] += __shfl_xor(csl[3], m);
    }
    if (lm == 0) {
        #pragma unroll
        for (int r = 0; r < 4; ++r) {
            int s = sbase + r;
            if (s < 7) bsum[wv][s] = csl[r];
        }
    }
    // partials into the (now dead) stage buffer
    #pragma unroll
    for (int dt = 0; dt < 8; ++dt)
        #pragma unroll
        for (int r = 0; r < 4; ++r) {
            int s = sbase + r;
            if (s < 7) prt[s * 132 + dt * 16 + lm] = uacc[dt][r];
        }
    __syncthreads();
    if (t < 128) {
        const float* p0 = (const float*)stage[0];
        const float* p1 = (const float*)stage[1];
        const float* p2 = (const float*)stage[2];
        const float* p3 = (const float*)stage[3];
        #pragma unroll
        for (int s = 0; s < 7; ++s) {
            int o = s * 132 + t;
            upart[((b * 16 + chunk) * 7 + s) * 128 + t] = p0[o] + p1[o] + p2[o] + p3[o];
        }
    }
    if (t < 7)
        cpart[(b * 16 + chunk) * 7 + t] = bsum[0][t] + bsum[1][t] + bsum[2][t] + bsum[3][t];
}

// ---------------------------------------------------------------------------
// K3 (one block per batch, 256 thr): P = reduce(upart); u = (P@Wv^T)/csum via
// MFMA; GRU via MFMA; LN; MLP via MFMA; dst; if hasq: LN + q + kq -> kqbf.
// R2-proven.
// ---------------------------------------------------------------------------
__global__ __launch_bounds__(256) void k_fused(
    const float* __restrict__ upart, const float* __restrict__ cpart,
    float* __restrict__ slots, const uint16_t* __restrict__ wbf,
    const float* __restrict__ bih, const float* __restrict__ bhh,
    const float* __restrict__ gm, const float* __restrict__ bm,
    const float* __restrict__ b1, const float* __restrict__ b2,
    const float* __restrict__ lsg, const float* __restrict__ lsb,
    uint16_t* __restrict__ kqbf, float* __restrict__ dst, int hasq) {
    __shared__ float uf[16][132];     // u, then hn, then sn(for q)
    __shared__ float hf[16][132];     // h, then out
    __shared__ float slf[16][132];    // P, then LN(hn), then q
    __shared__ float hidl[16][264];   // MLP hidden, then kq
    __shared__ float glg[7][776];
    __shared__ float csl[7];
    const int b = blockIdx.x;
    const int t = threadIdx.x, wv = t >> 6, lane = t & 63;
    const int lm = lane & 15, qd = lane >> 4;

    if (t < 7) {
        float c = 0.f;
        #pragma unroll
        for (int i = 0; i < 16; ++i) c += cpart[(b * 16 + i) * 7 + t];
        csl[t] = c;
    }
    for (int idx = t; idx < 896; idx += 256) {
        int s = idx >> 7, d = idx & 127;
        float acc = 0.f;
        #pragma unroll
        for (int i = 0; i < 16; ++i) acc += upart[((b * 16 + i) * 7 + s) * 128 + d];
        slf[s][d] = acc;                       // P (pre-Wv, pre-renorm)
        hf[s][d] = slots[(b * 7 + s) * 128 + d];
    }
    __syncthreads();

    // u = (P @ Wv^T) / csum
    {
        bf16x8 apb[4];
        #pragma unroll
        for (int k0 = 0; k0 < 4; ++k0)
            #pragma unroll
            for (int j = 0; j < 8; ++j) apb[k0][j] = (__bf16)slf[lm][k0 * 32 + qd * 8 + j];
        #pragma unroll
        for (int i = 0; i < 2; ++i) {
            int dt = wv * 2 + i;
            f32x4 acc = {0.f, 0.f, 0.f, 0.f};
            #pragma unroll
            for (int k0 = 0; k0 < 4; ++k0) {
                bf16x8 bf = *(const bf16x8*)(wbf + WV_OFF + ((dt * 4 + k0) << 9) + lane * 8);
                acc = __builtin_amdgcn_mfma_f32_16x16x32_bf16(apb[k0], bf, acc, 0, 0, 0);
            }
            #pragma unroll
            for (int r = 0; r < 4; ++r) {
                int s = qd * 4 + r;
                if (s < 7) uf[s][dt * 16 + lm] = acc[r] / csl[s];
            }
        }
    }
    __syncthreads();

    bf16x8 au[4], ah[4];
    #pragma unroll
    for (int k0 = 0; k0 < 4; ++k0)
        #pragma unroll
        for (int j = 0; j < 8; ++j) {
            au[k0][j] = (__bf16)uf[lm][k0 * 32 + qd * 8 + j];
            ah[k0][j] = (__bf16)hf[lm][k0 * 32 + qd * 8 + j];
        }
    {
        const int ih = (wv < 2);
        const uint16_t* W = wbf + (ih ? WIH_OFF : WHH_OFF);
        const int base = ih ? 0 : 384;
        const int w2 = wv & 1;
        #pragma unroll
        for (int i = 0; i < 12; ++i) {
            int ot = w2 * 12 + i;
            f32x4 acc = {0.f, 0.f, 0.f, 0.f};
            #pragma unroll
            for (int k0 = 0; k0 < 4; ++k0) {
                bf16x8 bf = *(const bf16x8*)(W + ((ot * 4 + k0) << 9) + lane * 8);
                acc = __builtin_amdgcn_mfma_f32_16x16x32_bf16(ih ? au[k0] : ah[k0], bf, acc, 0, 0, 0);
            }
            #pragma unroll
            for (int r = 0; r < 4; ++r) {
                int s = qd * 4 + r;
                if (s < 7) glg[s][base + ot * 16 + lm] = acc[r];
            }
        }
    }
    __syncthreads();

    for (int idx = t; idx < 896; idx += 256) {
        int s = idx >> 7, d = idx & 127;
        float xr = glg[s][d] + bih[d];
        float xz = glg[s][128 + d] + bih[128 + d];
        float xg = glg[s][256 + d] + bih[256 + d];
        float hr = glg[s][384 + d] + bhh[d];
        float hz = glg[s][512 + d] + bhh[128 + d];
        float hg = glg[s][640 + d] + bhh[256 + d];
        float r = 1.f / (1.f + __expf(-(xr + hr)));
        float z = 1.f / (1.f + __expf(-(xz + hz)));
        float n = tanhf(xg + r * hg);
        uf[s][d] = (1.f - z) * n + z * hf[s][d];
    }
    __syncthreads();

    for (int s = wv; s < 7; s += 4) {
        float a0 = uf[s][2 * lane], a1 = uf[s][2 * lane + 1];
        float sm = a0 + a1, sq = a0 * a0 + a1 * a1;
        #pragma unroll
        for (int m = 1; m < 64; m <<= 1) { sm += __shfl_xor(sm, m); sq += __shfl_xor(sq, m); }
        float mean = sm * (1.0f / 128.0f);
        float var = sq * (1.0f / 128.0f) - mean * mean;
        float rs = rsqrtf(var + LN_EPS_);
        slf[s][2 * lane]     = (a0 - mean) * rs * gm[2 * lane] + bm[2 * lane];
        slf[s][2 * lane + 1] = (a1 - mean) * rs * gm[2 * lane + 1] + bm[2 * lane + 1];
    }
    __syncthreads();

    bf16x8 as_[4];
    #pragma unroll
    for (int k0 = 0; k0 < 4; ++k0)
        #pragma unroll
        for (int j = 0; j < 8; ++j) as_[k0][j] = (__bf16)slf[lm][k0 * 32 + qd * 8 + j];
    #pragma unroll
    for (int i = 0; i < 4; ++i) {
        int ot = wv * 4 + i;
        f32x4 acc = {0.f, 0.f, 0.f, 0.f};
        #pragma unroll
        for (int k0 = 0; k0 < 4; ++k0) {
            bf16x8 bf = *(const bf16x8*)(wbf + W1_OFF + ((ot * 4 + k0) << 9) + lane * 8);
            acc = __builtin_amdgcn_mfma_f32_16x16x32_bf16(as_[k0], bf, acc, 0, 0, 0);
        }
        #pragma unroll
        for (int r = 0; r < 4; ++r) {
            int s = qd * 4 + r;
            if (s < 7) hidl[s][ot * 16 + lm] = fmaxf(acc[r] + b1[ot * 16 + lm], 0.f);
        }
    }
    __syncthreads();

    bf16x8 ahd[8];
    #pragma unroll
    for (int k0 = 0; k0 < 8; ++k0)
        #pragma unroll
        for (int j = 0; j < 8; ++j) ahd[k0][j] = (__bf16)hidl[lm][k0 * 32 + qd * 8 + j];
    #pragma unroll
    for (int i = 0; i < 2; ++i) {
        int ot = wv * 2 + i;
        f32x4 acc = {0.f, 0.f, 0.f, 0.f};
        #pragma unroll
        for (int k0 = 0; k0 < 8; ++k0) {
            bf16x8 bf = *(const bf16x8*)(wbf + W2_OFF + ((ot * 8 + k0) << 9) + lane * 8);
            acc = __builtin_amdgcn_mfma_f32_16x16x32_bf16(ahd[k0], bf, acc, 0, 0, 0);
        }
        #pragma unroll
        for (int r = 0; r < 4; ++r) {
            int s = qd * 4 + r;
            if (s < 7) {
                float v = slf[s][ot * 16 + lm] + acc[r] + b2[ot * 16 + lm];
                hf[s][ot * 16 + lm] = v;
                dst[(b * 7 + s) * 128 + ot * 16 + lm] = v;
            }
        }
    }
    if (hasq) {
        __syncthreads();
        // sn = LN_slots(out) -> uf
        for (int s = wv; s < 7; s += 4) {
            float a0 = hf[s][2 * lane], a1 = hf[s][2 * lane + 1];
            float sm = a0 + a1, sq = a0 * a0 + a1 * a1;
            #pragma unroll
            for (int m = 1; m < 64; m <<= 1) { sm += __shfl_xor(sm, m); sq += __shfl_xor(sq, m); }
            float mean = sm * (1.0f / 128.0f);
            float var = sq * (1.0f / 128.0f) - mean * mean;
            float rs = rsqrtf(var + LN_EPS_);
            uf[s][2 * lane]     = (a0 - mean) * rs * lsg[2 * lane] + lsb[2 * lane];
            uf[s][2 * lane + 1] = (a1 - mean) * rs * lsg[2 * lane + 1] + lsb[2 * lane + 1];
        }
        __syncthreads();
        // q = sn @ Wq^T -> slf
        bf16x8 an[4];
        #pragma unroll
        for (int k0 = 0; k0 < 4; ++k0)
            #pragma unroll
            for (int j = 0; j < 8; ++j) an[k0][j] = (__bf16)uf[lm][k0 * 32 + qd * 8 + j];
        #pragma unroll
        for (int i = 0; i < 2; ++i) {
            int ot = wv * 2 + i;
            f32x4 acc = {0.f, 0.f, 0.f, 0.f};
            #pragma unroll
            for (int k0 = 0; k0 < 4; ++k0) {
                bf16x8 bf = *(const bf16x8*)(wbf + WQ_OFF + ((ot * 4 + k0) << 9) + lane * 8);
                acc = __builtin_amdgcn_mfma_f32_16x16x32_bf16(an[k0], bf, acc, 0, 0, 0);
            }
            #pragma unroll
            for (int r = 0; r < 4; ++r) {
                int s = qd * 4 + r;
                if (s < 7) slf[s][ot * 16 + lm] = acc[r];
            }
        }
        __syncthreads();
        // kq = q @ Wk -> hidl
        bf16x8 aq[4];
        #pragma unroll
        for (int k0 = 0; k0 < 4; ++k0)
            #pragma unroll
            for (int j = 0; j < 8; ++j) aq[k0][j] = (__bf16)slf[lm][k0 * 32 + qd * 8 + j];
        #pragma unroll
        for (int i = 0; i < 2; ++i) {
            int dt = wv * 2 + i;
            f32x4 acc = {0.f, 0.f, 0.f, 0.f};
            #pragma unroll
            for (int k0 = 0; k0 < 4; ++k0) {
                bf16x8 bf = *(const bf16x8*)(wbf + WKT_OFF + ((dt * 4 + k0) << 9) + lane * 8);
                acc = __builtin_amdgcn_mfma_f32_16x16x32_bf16(aq[k0], bf, acc, 0, 0, 0);
            }
            #pragma unroll
            for (int r = 0; r < 4; ++r) {
                int s = qd * 4 + r;
                if (s < 7) hidl[s][dt * 16 + lm] = acc[r];
            }
        }
        __syncthreads();
        // frag-linear bf16 store of kq*SC
        {
            int kt = t >> 6, lp = t & 63;
            int lmp = lp & 15, qdp = lp >> 4;
            uint16_t h[8];
            #pragma unroll
            for (int j = 0; j < 8; ++j)
                h[j] = (lmp < 7) ? f2bfbits(hidl[lmp][kt * 32 + qdp * 8 + j] * SC_INV) : (uint16_t)0;
            uint4 st;
            st.x = (uint32_t)h[0] | ((uint32_t)h[1] << 16);
            st.y = (uint32_t)h[2] | ((uint32_t)h[3] << 16);
            st.z = (uint32_t)h[4] | ((uint32_t)h[5] << 16);
            st.w = (uint32_t)h[6] | ((uint32_t)h[7] << 16);
            *(uint4*)(kqbf + b * 2048 + t * 8) = st;
        }
    }
}

// ---------------------------------------------------------------------------
extern "C" void kernel_launch(void* const* d_in, const int* in_sizes, int n_in,
                              void* d_out, int out_size, void* d_ws, size_t ws_size,
                              hipStream_t stream) {
    const float* x    = (const float*)d_in[0];
    const float* nz   = (const float*)d_in[1];
    const float* Wq   = (const float*)d_in[2];
    const float* Wk   = (const float*)d_in[3];
    const float* Wv   = (const float*)d_in[4];
    const float* ling = (const float*)d_in[5];
    const float* linb = (const float*)d_in[6];
    const float* lsg  = (const float*)d_in[7];
    const float* lsb  = (const float*)d_in[8];
    const float* lmg  = (const float*)d_in[9];
    const float* lmb  = (const float*)d_in[10];
    const float* Wih  = (const float*)d_in[11];
    const float* Whh  = (const float*)d_in[12];
    const float* bih  = (const float*)d_in[13];
    const float* bhh  = (const float*)d_in[14];
    const float* W1   = (const float*)d_in[15];
    const float* b1   = (const float*)d_in[16];
    const float* W2   = (const float*)d_in[17];
    const float* b2   = (const float*)d_in[18];
    const float* mu   = (const float*)d_in[19];
    const float* lsig = (const float*)d_in[20];

    char* wsb = (char*)d_ws;
    uint16_t* xn    = (uint16_t*)(wsb);                        // 67108864 B
    uint16_t* wbf   = (uint16_t*)(wsb + (size_t)67108864);     // 425984 B
    uint16_t* kqbf  = (uint16_t*)(wsb + (size_t)67534848);     // 262144 B
    float*    slots = (float*)  (wsb + (size_t)67796992);      // 229376 B
    float*    upart = (float*)  (wsb + (size_t)68026368);      // 3670016 B
    float*    cpart = (float*)  (wsb + (size_t)71696384);      // 28672 B

    k_init_prep<<<4544, 256, 0, stream>>>(nz, Wk, mu, lsig, Wq, lsg, lsb,
                                          Wih, Whh, W1, W2, Wv, slots, kqbf, wbf,
                                          x, ling, linb, xn);
    for (int it = 0; it < 3; ++it) {
        float* dst = (it == 2) ? (float*)d_out : slots;
        k_attn<<<1024, 256, 0, stream>>>(xn, kqbf, upart, cpart);
        k_fused<<<64, 256, 0, stream>>>(upart, cpart, slots, wbf, bih, bhh,
                                        lmg, lmb, b1, b2, lsg, lsb,
                                        kqbf, dst, (it < 2) ? 1 : 0);
    }
}